// Round 9
// baseline (2616.473 us; speedup 1.0000x reference)
//
#include <hip/hip_runtime.h>
#include <hip/hip_bf16.h>

#define RMAX 40
#define HH   512
#define WW   512
#define CC   3
#define BB   64
#define ROWS 4     // h-rows per passB virtual block
#define LROW 592   // f16 elements per LDS row
#define NBLK 2048  // 8 blocks/CU x 256 CU, guaranteed co-resident

typedef unsigned short u16;
typedef __attribute__((ext_vector_type(8))) short short8;   // 8 bf16 MFMA A/B frag
typedef __attribute__((ext_vector_type(4))) float f32x4;    // MFMA C/D frag + 16B loads
typedef _Float16 h2 __attribute__((ext_vector_type(2)));
typedef _Float16 h8 __attribute__((ext_vector_type(8)));
typedef __attribute__((ext_vector_type(8))) u16 u16x8;

__device__ __forceinline__ u16 f2bf(float f) {
    unsigned u = __float_as_uint(f);
    u += 0x7FFFu + ((u >> 16) & 1u);
    return (u16)(u >> 16);
}
__device__ __forceinline__ float bf2f(u16 s) {
    return __uint_as_float(((unsigned)s) << 16);
}
__device__ __forceinline__ u16 h2u16(_Float16 h) { return __builtin_bit_cast(u16, h); }

__device__ __forceinline__ float fdot2w(h2 a, unsigned wpk, float c) {
#if __has_builtin(__builtin_amdgcn_fdot2)
    return __builtin_amdgcn_fdot2(a, __builtin_bit_cast(h2, wpk), c, false);
#else
    h2 wv = __builtin_bit_cast(h2, wpk);
    return c + (float)a.x * (float)wv.x + (float)a.y * (float)wv.y;
#endif
}

// ---------------------------------------------------------------------------
// Generation-counting grid barrier (no cooperative API; graph-capture safe).
// Requires all NBLK blocks co-resident (guaranteed by launch_bounds + LDS).
// cnt self-resets each use; gen monotonically increases. Bounded spin (~1s)
// turns a residency bug into a wrong answer instead of a hang.
// ---------------------------------------------------------------------------
__device__ void gbar(unsigned* cnt, unsigned* gen) {
    __syncthreads();
    if (threadIdx.x == 0) {
        __threadfence();
        unsigned g = __hip_atomic_load(gen, __ATOMIC_RELAXED, __HIP_MEMORY_SCOPE_AGENT);
        unsigned a = __hip_atomic_fetch_add(cnt, 1u, __ATOMIC_ACQ_REL, __HIP_MEMORY_SCOPE_AGENT);
        if (a == NBLK - 1u) {
            __hip_atomic_store(cnt, 0u, __ATOMIC_RELAXED, __HIP_MEMORY_SCOPE_AGENT);
            __hip_atomic_store(gen, g + 1u, __ATOMIC_RELEASE, __HIP_MEMORY_SCOPE_AGENT);
        } else {
            long long t = 0;
            while (__hip_atomic_load(gen, __ATOMIC_ACQUIRE, __HIP_MEMORY_SCOPE_AGENT) == g) {
                if (++t > (1LL << 28)) break;     // safety valve
            }
        }
        __threadfence();
    }
    __syncthreads();
}

// ---------------------------------------------------------------------------
// Phase bodies (R7-verified, unchanged).
// ---------------------------------------------------------------------------
__device__ void do_prep(int b, int tid,
                        const float* __restrict__ sigmas10,
                        const int*   __restrict__ steps,
                        int* __restrict__ rbuf, float* __restrict__ mbuf,
                        unsigned* __restrict__ ptab, u16* __restrict__ atab)
{
    const float sigma = sigmas10[steps[b]];
    int r = (int)floorf(4.0f * sigma + 0.5f);
    if (r > RMAX) r = RMAX;
    const float s2 = sigma * sigma;

    float sum = 0.0f;
    for (int p = -r; p <= r; ++p)
        sum += expf(-0.5f * (float)(p * p) / s2);
    const float inv = 1.0f / sum;

    auto kval = [&](int i) -> float {           // kpad[i] = k_{i-56}
        int p = i - 56;
        if (p < -r || p > r) return 0.0f;
        return expf(-0.5f * (float)(p * p) / s2) * inv;
    };

    if (tid < 64) {                             // even-paired table E
        float a = kval(2 * tid), bb = kval(2 * tid + 1);
        ptab[b * 128 + tid] = (unsigned)h2u16((_Float16)a)
                            | ((unsigned)h2u16((_Float16)bb) << 16);
    } else if (tid < 128) {                     // staggered table O
        int m = tid - 64;
        float a = kval(2 * m - 1), bb = kval(2 * m);
        ptab[b * 128 + 64 + m] = (unsigned)h2u16((_Float16)a)
                               | ((unsigned)h2u16((_Float16)bb) << 16);
    }

    if (tid == 0) {
        rbuf[b] = r;
        float Mm[9];
        for (int i = 0; i < 9; ++i) Mm[i] = 0.0f;
        for (int p = -r; p <= r; ++p) {
            float wv = expf(-0.5f * (float)(p * p) / s2) * inv;
            for (int c = 0; c < CC; ++c) {
                int i = c + p;
                int j = ((i % 6) + 6) % 6;      // reflect n=3 -> period 6
                int cc = (j < 3) ? j : 5 - j;
                Mm[c * 3 + cc] += wv;
            }
        }
        for (int c = 0; c < 3; ++c)
            for (int cc = 0; cc < 3; ++cc)
                mbuf[b * 12 + c * 4 + cc] = Mm[c * 3 + cc];
    }

    u16* ab = atab + (size_t)b * 8192;          // bf16 hi/lo Toeplitz for passC
    int e = tid * 32;
    for (int ee = 0; ee < 32; ++ee, ++e) {
        int j    = e & 7;
        int lane = (e >> 3) & 63;
        int s    = e >> 9;
        int ch   = s >> 2;
        int half = (s >> 1) & 1;
        int prec = s & 1;
        int m = 32 * ch + ((lane >> 4) << 3) + j - (lane & 15) - 16 * half;
        float wfull = 0.0f;
        if (m >= 0 && m <= 2 * r) {
            int p = m - r;
            wfull = expf(-0.5f * (float)(p * p) / s2) * inv;
        }
        u16 hi = f2bf(wfull);
        u16 val = hi;
        if (prec) val = f2bf(wfull - bf2f(hi));
        ab[e] = val;
    }
}

__device__ void do_passB(int b, int h0, int tid, u16 (*mixs)[LROW],
                         const float* __restrict__ x,
                         const unsigned* __restrict__ ptab,
                         const float* __restrict__ mbuf,
                         const int* __restrict__ rbuf,
                         u16* __restrict__ out1)
{
    __syncthreads();                            // LDS reuse across iterations
    const int r = __builtin_amdgcn_readfirstlane(rbuf[b]);

    const float M00 = mbuf[b * 12 + 0], M01 = mbuf[b * 12 + 1], M02 = mbuf[b * 12 + 2];
    const float M10 = mbuf[b * 12 + 4], M11 = mbuf[b * 12 + 5], M12 = mbuf[b * 12 + 6];
    const float M20 = mbuf[b * 12 + 8], M21 = mbuf[b * 12 + 9], M22 = mbuf[b * 12 + 10];

    const float* xb = x + (size_t)b * CC * HH * WW + (size_t)h0 * WW;

#pragma unroll
    for (int it = 0; it < 2; ++it) {            // interior staging
        int idx = tid + 256 * it;
        int row = idx >> 7;                     // 0..3
        int w   = (idx & 127) << 2;             // 0..508
        const float* px = xb + (size_t)row * WW + w;
        f32x4 c0 = __builtin_nontemporal_load((const f32x4*)px);
        f32x4 c1 = __builtin_nontemporal_load((const f32x4*)(px + HH * WW));
        f32x4 c2 = __builtin_nontemporal_load((const f32x4*)(px + 2 * HH * WW));
        f32x4 m0 = M00 * c0 + M01 * c1 + M02 * c2;
        f32x4 m1 = M10 * c0 + M11 * c1 + M12 * c2;
        f32x4 m2 = M20 * c0 + M21 * c1 + M22 * c2;
        ushort4 o0, o1, o2;
        o0.x = h2u16((_Float16)m0.x); o0.y = h2u16((_Float16)m0.y);
        o0.z = h2u16((_Float16)m0.z); o0.w = h2u16((_Float16)m0.w);
        o1.x = h2u16((_Float16)m1.x); o1.y = h2u16((_Float16)m1.y);
        o1.z = h2u16((_Float16)m1.z); o1.w = h2u16((_Float16)m1.w);
        o2.x = h2u16((_Float16)m2.x); o2.y = h2u16((_Float16)m2.y);
        o2.z = h2u16((_Float16)m2.z); o2.w = h2u16((_Float16)m2.w);
        *(ushort4*)&mixs[0 * ROWS + row][RMAX + w] = o0;
        *(ushort4*)&mixs[1 * ROWS + row][RMAX + w] = o1;
        *(ushort4*)&mixs[2 * ROWS + row][RMAX + w] = o2;
    }
#pragma unroll
    for (int it = 0; it < 2; ++it) {            // halo staging
        int hidx = tid + 256 * it;
        if (hidx < ROWS * 2 * RMAX) {
            int row = hidx & 3;
            int pos = hidx >> 2;                        // 0..79
            int wi  = (pos < RMAX) ? pos : (WW + pos);  // [0,40) U [552,592)
            int lw  = wi - RMAX;
            int jm  = lw & (2 * WW - 1);
            int src = (jm < WW) ? jm : (2 * WW - 1 - jm);
            const float* px = xb + (size_t)row * WW + src;
            float a0 = __builtin_nontemporal_load(px);
            float a1 = __builtin_nontemporal_load(px + HH * WW);
            float a2 = __builtin_nontemporal_load(px + 2 * HH * WW);
            mixs[0 * ROWS + row][wi] = h2u16((_Float16)(M00 * a0 + M01 * a1 + M02 * a2));
            mixs[1 * ROWS + row][wi] = h2u16((_Float16)(M10 * a0 + M11 * a1 + M12 * a2));
            mixs[2 * ROWS + row][wi] = h2u16((_Float16)(M20 * a0 + M21 * a1 + M22 * a2));
        }
    }
    __syncthreads();

    const int i0off = (RMAX - r) & ~7;
    const int base0 = (16 + i0off) >> 1;
    const int nck   = ((((RMAX - r) & 7) + 7 + 2 * r) >> 3) + 1;  // covers q=7 tail
    const unsigned* et = ptab + b * 128;
    const unsigned* ot = et + 64;

#pragma unroll
    for (int k = 0; k < 3; ++k) {
        const int task = tid + 256 * k;
        const int g    = task & 63;
        const int rc   = task >> 6;             // c = rc>>2, row = rc&3
        const int w0   = g << 3;
        const u16* L   = &mixs[rc][0];
        const int ib   = w0 + i0off;

        float a0 = 0.f, a1 = 0.f, a2 = 0.f, a3 = 0.f;
        float a4 = 0.f, a5 = 0.f, a6 = 0.f, a7 = 0.f;

        for (int c = 0; c < nck; ++c) {
            h8 D = *(const h8*)(L + ib + 8 * c);
            int mi = base0 + 4 * c;
#pragma unroll
            for (int u = 0; u < 4; ++u) {
                h2 dp = { D[2 * u], D[2 * u + 1] };
                a0 = fdot2w(dp, et[mi + u],     a0);
                a1 = fdot2w(dp, ot[mi + u],     a1);
                a2 = fdot2w(dp, et[mi + u - 1], a2);
                a3 = fdot2w(dp, ot[mi + u - 1], a3);
                a4 = fdot2w(dp, et[mi + u - 2], a4);
                a5 = fdot2w(dp, ot[mi + u - 2], a5);
                a6 = fdot2w(dp, et[mi + u - 3], a6);
                a7 = fdot2w(dp, ot[mi + u - 3], a7);
            }
        }

        const int cch = rc >> 2, row = rc & 3;
        u16x8 o = { f2bf(a0), f2bf(a1), f2bf(a2), f2bf(a3),
                    f2bf(a4), f2bf(a5), f2bf(a6), f2bf(a7) };
        u16* dst = out1 + ((size_t)b * CC + cch) * HH * WW
                 + (size_t)(h0 + row) * WW + w0;
        *(u16x8*)dst = o;
    }
}

__device__ __forceinline__ int refl512(int i) {
    int jm = i & (2 * HH - 1);
    return (jm < HH) ? jm : (2 * HH - 1 - jm);
}

__device__ void do_passC(int wtile, int h0i, int bc, int tid,
                         const u16* __restrict__ in1,
                         const u16* __restrict__ atab,
                         const int* __restrict__ rbuf,
                         float* __restrict__ out)
{
    const int lane = tid & 63;
    const int b    = bc / 3;
    const int r    = __builtin_amdgcn_readfirstlane(rbuf[b]);
    const int h0   = h0i * 32;
    const int w    = wtile * 64 + (tid >> 6) * 16 + (lane & 15);
    const int nch  = (2 * r + 63) >> 5;
    const int rowbase = h0 - r + ((lane >> 4) << 3);

    const u16* src = in1 + (size_t)bc * HH * WW + w;
    const short8* at = (const short8*)(atab + (size_t)b * 8192);

    f32x4 acc0 = {0.f, 0.f, 0.f, 0.f};
    f32x4 acc1 = {0.f, 0.f, 0.f, 0.f};

    for (int ch = 0; ch < nch; ++ch) {
        short8 bv;
#pragma unroll
        for (int j = 0; j < 8; ++j) {
            int row = refl512(rowbase + 32 * ch + j);
            bv[j] = (short)src[(size_t)row * WW];
        }
        short8 ah0 = at[(ch * 4 + 0) * 64 + lane];
        short8 al0 = at[(ch * 4 + 1) * 64 + lane];
        short8 ah1 = at[(ch * 4 + 2) * 64 + lane];
        short8 al1 = at[(ch * 4 + 3) * 64 + lane];

        acc0 = __builtin_amdgcn_mfma_f32_16x16x32_bf16(ah0, bv, acc0, 0, 0, 0);
        acc0 = __builtin_amdgcn_mfma_f32_16x16x32_bf16(al0, bv, acc0, 0, 0, 0);
        acc1 = __builtin_amdgcn_mfma_f32_16x16x32_bf16(ah1, bv, acc1, 0, 0, 0);
        acc1 = __builtin_amdgcn_mfma_f32_16x16x32_bf16(al1, bv, acc1, 0, 0, 0);
    }

    const int orow = h0 + ((lane >> 4) << 2);
    float* dst = out + (size_t)bc * HH * WW + (size_t)orow * WW + w;
#pragma unroll
    for (int q = 0; q < 4; ++q) {
        __builtin_nontemporal_store(acc0[q], dst + (size_t)q * WW);
        __builtin_nontemporal_store(acc1[q], dst + (size_t)(q + 16) * WW);
    }
}

// ---------------------------------------------------------------------------
// Fused persistent kernel: prep -> [gbar] -> passB x4 -> [gbar] -> passC x12.
// 2048 blocks co-resident by construction: __launch_bounds__(256,8) = 8
// waves/SIMD = 8 blocks/CU; LDS 14.2 KiB (cap 11/CU); 8 x 256 CU = 2048.
// passC virtual blocks walk h0 fastest within (bc,wtile): consecutive
// h-tiles overlap 2r inter rows -> L1/L2 reuse.
// ---------------------------------------------------------------------------
__global__ __launch_bounds__(256, 8) void fused_kernel(
    const float* __restrict__ x, const float* __restrict__ sigmas10,
    const int* __restrict__ steps, int* __restrict__ rbuf,
    float* __restrict__ mbuf, unsigned* __restrict__ ptab,
    u16* __restrict__ atab, u16* __restrict__ inter, float* __restrict__ out,
    unsigned* __restrict__ bar)
{
    __shared__ __align__(16) u16 mixs[CC * ROWS][LROW];
    const int rb  = blockIdx.x;
    const int tid = threadIdx.x;

    if (rb < BB)
        do_prep(rb, tid, sigmas10, steps, rbuf, mbuf, ptab, atab);
    gbar(bar, bar + 1);

#pragma unroll 1
    for (int i = 0; i < 4; ++i) {               // 8192 virtual passB blocks
        int vb = rb * 4 + i;                    // b = vb>>7, 4 consecutive h-tiles
        do_passB(vb >> 7, (vb & 127) * ROWS, tid, mixs, x, ptab, mbuf, rbuf, inter);
    }
    gbar(bar, bar + 1);

#pragma unroll 1
    for (int i = 0; i < 12; ++i) {              // 24576 virtual passC blocks
        int vb = rb * 12 + i;                   // bc = vb>>7, h0 fastest
        do_passC((vb >> 4) & 7, vb & 15, vb >> 7, tid, inter, atab, rbuf, out);
    }
}

// ---------------------------------------------------------------------------
extern "C" void kernel_launch(void* const* d_in, const int* in_sizes, int n_in,
                              void* d_out, int out_size, void* d_ws, size_t ws_size,
                              hipStream_t stream)
{
    const float* x      = (const float*)d_in[0];
    const float* sigmas = (const float*)d_in[1];
    const int*   steps  = (const int*)d_in[2];
    float*       out    = (float*)d_out;

    int*      rbuf  = (int*)d_ws;                              // 256 B
    float*    mbuf  = (float*)((char*)d_ws + 256);             // 3 KB
    unsigned* bar   = (unsigned*)((char*)d_ws + 3456);         // 64 B barrier state
    unsigned* ptab  = (unsigned*)((char*)d_ws + 4096);         // 32 KB pair tables
    u16*      atab  = (u16*)((char*)d_ws + 65536);             // 1 MiB A-frag table
    u16*      inter = (u16*)((char*)d_ws + 65536 + (1 << 20)); // 96 MiB bf16

    hipMemsetAsync(bar, 0, 64, stream);         // cnt=0, gen=0 (captured in graph)

    fused_kernel<<<NBLK, 256, 0, stream>>>(x, sigmas, steps, rbuf, mbuf,
                                           ptab, atab, inter, out, bar);
}